// Round 1
// baseline (211.284 us; speedup 1.0000x reference)
//
#include <hip/hip_runtime.h>

// FusedMultiPool: out[b,s,h,w] = max_{k<K} x[b, idx[s,k], h, w]
// B=32, C=256, H=64, W=64, S=128, K=8. fp32.
//
// v2: LDS inversion -> single-pass HBM.
// The previous gather kernel read each x element ~SK/C = 4x through L2/L3
// (512 MiB cache-side traffic). Here each block stages x[b, 0:256, tile]
// (16 float4 positions x 256 channels = 64 KiB) into LDS ONCE, then computes
// all 128 outputs for that (b,tile) from LDS. x is read from HBM exactly
// once overall: 134 MB read + 67 MB write ~= 30 us floor at 6.6 TB/s.
//
// Block = 256 threads, LDS = 68 KiB -> 2 blocks/CU (launch_bounds(256,2):
// 2 waves/SIMD = 8 waves/CU). Grid = 32 b * 64 tiles = 2048 blocks
// = exactly 4 rounds of 2 blocks on each of 256 CUs.

constexpr int Bb = 32, Cc = 256, Hh = 64, Ww = 64, Ss = 128, Kk = 8;
constexpr int HW4 = (Hh * Ww) / 4;  // 1024 float4 per channel plane
constexpr int T4  = 16;             // float4 positions per tile
constexpr int NT  = HW4 / T4;       // 64 tiles per b

__global__ __launch_bounds__(256, 2) void fmp_kernel(
    const float4* __restrict__ x4,
    const int*    __restrict__ idx,
    float4*       __restrict__ out4)
{
    __shared__ float4 lx[Cc * T4];          // 64 KiB: lx[c*16 + t]
    __shared__ int4   lidx4[Ss * Kk / 4];   // 4 KiB: channel index sets

    const int tid  = threadIdx.x;
    const int tile = blockIdx.x & (NT - 1);
    const int b    = blockIdx.x >> 6;       // NT = 64

    // stage channel-index sets: 1024 ints, one int4 per thread, coalesced
    lidx4[tid] = ((const int4*)idx)[tid];

    // stage x[b, :, tile*16 .. tile*16+16) : 256 ch x 16 float4, one pass.
    // flat = i*256 + tid -> 16-lane groups read 256 B contiguous per channel;
    // LDS writes are 1 KiB contiguous per wave (conflict-free).
    const float4* __restrict__ xb = x4 + (size_t)b * (Cc * HW4) + tile * T4;
    #pragma unroll
    for (int i = 0; i < 16; ++i) {
        const int flat = i * 256 + tid;     // float4 index into lx
        const int c    = flat >> 4;
        const int tt   = flat & (T4 - 1);
        lx[flat] = xb[(size_t)c * HW4 + tt];
    }
    __syncthreads();

    // compute: thread handles t = tid&15, s = pass*16 + (tid>>4).
    // idx reads are uniform within each 16-lane group -> LDS broadcast.
    const int t = tid & (T4 - 1);
    float4* __restrict__ op = out4 + (size_t)b * (Ss * HW4) + tile * T4 + t;

#define FMAX4(m, c) { const float4 v = lx[(c) * T4 + t];          \
        m.x = fmaxf(m.x, v.x); m.y = fmaxf(m.y, v.y);             \
        m.z = fmaxf(m.z, v.z); m.w = fmaxf(m.w, v.w); }

    #pragma unroll
    for (int pass = 0; pass < 8; ++pass) {
        const int s   = pass * 16 + (tid >> 4);
        const int4 i0 = lidx4[s * 2];
        const int4 i1 = lidx4[s * 2 + 1];
        float4 m = lx[i0.x * T4 + t];
        FMAX4(m, i0.y); FMAX4(m, i0.z); FMAX4(m, i0.w);
        FMAX4(m, i1.x); FMAX4(m, i1.y); FMAX4(m, i1.z); FMAX4(m, i1.w);
        op[(size_t)s * HW4] = m;            // 256 B chunks per 16-lane group
    }
#undef FMAX4
}

extern "C" void kernel_launch(void* const* d_in, const int* in_sizes, int n_in,
                              void* d_out, int out_size, void* d_ws, size_t ws_size,
                              hipStream_t stream) {
    const float4* x4  = (const float4*)d_in[0];
    const int*    idx = (const int*)d_in[1];
    float4*       o4  = (float4*)d_out;

    const int blocks = Bb * NT;   // 2048
    fmp_kernel<<<blocks, 256, 0, stream>>>(x4, idx, o4);
}